// Round 8
// baseline (1354.343 us; speedup 1.0000x reference)
//
#include <hip/hip_runtime.h>
#include <utility>

// SPDConv2D: recursive weighted geometric mean of 8x8 SPD matrices.
// One wave per (o,site) chain; lane l holds element (i,j)=(l>>3,l&7).
// R7: XOR (hypercube) Jacobi pairing — partner = index ^ r, r=1..7.
//     All per-round cross-lane fetches become self-address XOR constants,
//     issued as ONE parallel DS level; column rotation computed locally
//     (no dependent param hop). Single serial DS hop per round.

static __device__ __forceinline__ float bper(int byteidx, float v) {
  return __int_as_float(__builtin_amdgcn_ds_bpermute(byteidx, __float_as_int(v)));
}
static __device__ __forceinline__ float rl(float v, int lane_u) {
  return __int_as_float(__builtin_amdgcn_readlane(__float_as_int(v), lane_u));
}
static __device__ __forceinline__ float rcpf_(float x) { return __builtin_amdgcn_rcpf(x); }
static __device__ __forceinline__ float rsqf_(float x) { return __builtin_amdgcn_rsqf(x); }

// Broadcast octet position R (0..7) to all 8 lanes of each octet (DPP only).
template <int R>
static __device__ __forceinline__ float obcast(float v, bool hi) {
  const int x = __float_as_int(v);
  const int a = __builtin_amdgcn_update_dpp(0, x, (R & 3) * 0x55, 0xF, 0xF, false);
  const int m = __builtin_amdgcn_update_dpp(0, a, 0x141, 0xF, 0xF, false);
  const int r = (R < 4) ? (hi ? m : a) : (hi ? a : m);
  return __int_as_float(r);
}

template <class F, int... Is>
static __device__ __forceinline__ void sfor_impl(F&& f, std::integer_sequence<int, Is...>) {
  (f(std::integral_constant<int, Is>{}), ...);
}
template <int N, class F>
static __device__ __forceinline__ void sfor(F&& f) {
  sfor_impl(static_cast<F&&>(f), std::make_integer_sequence<int, N>{});
}

__global__ __launch_bounds__(128) void spd_fm_kernel(
    const float* __restrict__ x,      // (4,8,20,20,8,8) f32
    const float* __restrict__ wm,     // (16,72) f32
    float* __restrict__ out)          // (4,16,9,9,8,8) f32
{
  const int wid = blockIdx.x * 2 + (threadIdx.x >> 6);
  if (wid >= 16 * 324) return;
  const int lane = threadIdx.x & 63;
  const int i = lane >> 3, j = lane & 7;
  const bool hi = (lane & 4) != 0;

  const int o    = wid / 324;
  const int site = wid - o * 324;
  const int b   = site / 81;
  const int r81 = site - b * 81;
  const int ho  = r81 / 9;
  const int wo  = r81 - ho * 9;

  const float* xb   = x + b * 204800 + (ho * 2) * 1280 + (wo * 2) * 64 + lane;
  const float* wrow = wm + o * 72;

  const int tp      = (((j << 3) | i)) << 2;  // transpose byte-index
  const int jj5     = j << 5;                 // byte base for src=(j<<3)|kk
  const int ii5     = i << 5;                 // byte base for src=(i<<3)|kk
  const int j2      = j << 2;                 // byte base for src=(r<<3)|j
  const int bx_ii   = (i * 9) << 2;           // lane (i,i)
  const int bx_jj   = (j * 9) << 2;           // lane (j,j)
  const int bx_self = lane << 2;              // own lane

  // t[o,k] = w^2/cumsum(w^2) (eps cancels); t0 == 1 => M = sym(X_0)
  float w0 = wrow[0];
  float csum = w0 * w0;
  float M = xb[0];
  M = 0.5f * (M + bper(tp, M));

  float Xc = xb[25600];  // k=1: kh=0,kw=0,c=1
  for (int k = 1; k < 72; ++k) {
    // prefetch X for k+1
    float Xn = 0.0f;
    if (k + 1 < 72) {
      const int k1 = k + 1;
      const int kh = k1 / 24;
      const int rr = k1 - kh * 24;
      Xn = xb[(rr & 7) * 25600 + kh * 1280 + (rr >> 3) * 64];
    }

    float wv = wrow[k];
    wv *= wv;
    csum += wv;
    const float tk = wv * rcpf_(csum);

    // ---- Cholesky M = L L^T ----
    float a = M;
    float dinv = 0.0f;  // diag lanes hold 1/L_kk
    sfor<8>([&](auto KK) {
      constexpr int kk = KK.value;
      const float akk  = fmaxf(rl(a, 9 * kk), 1e-20f);
      const float rinv = rsqf_(akk);
      if (j == kk) a = (i == kk) ? akk * rinv : a * rinv;
      if (i == kk && j == kk) dinv = rinv;
      const float lik = obcast<kk>(a, hi);          // L[i][kk] via DPP
      const float ljk = bper(jj5 | (kk << 2), a);   // L[j][kk]
      if (i > kk && j > kk) a = fmaf(-lik, ljk, a);
    });
    const float Lm = (j <= i) ? a : 0.0f;

    // prefetch L[i][r] for both solves: 8 independent bpermutes
    float lir[8];
    sfor<8>([&](auto RR) {
      constexpr int r = RR.value;
      lir[r] = bper(ii5 | (r << 2), Lm);
    });

    // ---- Y = L^{-1} X ----
    float y = Xc;
    sfor<8>([&](auto RR) {
      constexpr int r = RR.value;
      const float dr = rl(dinv, 9 * r);
      if (i == r) y *= dr;
      const float yr = bper((r << 5) | j2, y);      // Y[r][j] (serial)
      if (i > r) y = fmaf(-lir[r], yr, y);
    });

    // ---- Z = L^{-1} Y^T ----
    float z = bper(tp, y);
    sfor<8>([&](auto RR) {
      constexpr int r = RR.value;
      const float dr = rl(dinv, 9 * r);
      if (i == r) z *= dr;
      const float zr = bper((r << 5) | j2, z);
      if (i > r) z = fmaf(-lir[r], zr, z);
    });
    z = 0.5f * (z + bper(tp, z));

    // trace is rotation-invariant -> fixed absolute scale for convergence
    float trz = 0.0f;
#pragma unroll
    for (int d = 0; d < 8; ++d) trz += rl(z, 9 * d);
    const float s2 = 1.6e-8f * trz * trz;  // (~1e-3 * tr/8)^2

    // ---- XOR-paired Jacobi eigh, W = (L * prod J)^T by row-ops ----
    float W = bper(tp, Lm);
    auto jacobi_sweep = [&]() {
      sfor<7>([&](auto RR) {
        constexpr int r  = RR.value + 1;
        constexpr int xc = r << 2;        // col-xor on byte addr
        constexpr int xr = r << 5;        // row-xor on byte addr
        constexpr int xd = 36 * r;        // diag-lane xor: (9r)<<2
        // ONE parallel DS level: everything fetched from current z / W.
        const float dI  = bper(bx_ii, z);           // Z[i][i]
        const float dP  = bper(bx_ii ^ xd, z);      // Z[i^r][i^r]
        const float aR  = bper(bx_ii ^ xc, z);      // Z[i][i^r]
        const float dJ  = bper(bx_jj, z);           // Z[j][j]
        const float dPc = bper(bx_jj ^ xd, z);      // Z[j^r][j^r]
        const float aC  = bper(bx_jj ^ xc, z);      // Z[j][j^r]
        const float zr  = bper(bx_self ^ xr, z);    // Z[i^r][j]
        const float zc  = bper(bx_self ^ xc, z);    // Z[i][j^r]
        const float zrc = bper(bx_self ^ (xr | xc), z);  // Z[i^r][j^r]
        const float Wr  = bper(bx_self ^ xr, W);    // W[i^r][j]
        // row rotation (pair {i, i^r}); sign of dd absorbs p/q ordering
        const float ddR = dI - dP;
        const float qR  = aR + aR;
        const float h2R = fmaf(ddR, ddR, qR * qR);
        const float rhR = rsqf_(fmaxf(h2R, 1e-38f));
        const float c2R = fmaf(0.5f * fabsf(ddR), rhR, 0.5f);
        const float rcR = rsqf_(c2R);
        const float ccR = (h2R > 1e-38f) ? c2R * rcR : 1.0f;
        const float tR  = aR * (rhR * rcR);
        const float sR  = (ddR < 0.0f) ? -tR : tR;
        // col rotation (pair {j, j^r}) computed locally
        const float ddC = dJ - dPc;
        const float qC  = aC + aC;
        const float h2C = fmaf(ddC, ddC, qC * qC);
        const float rhC = rsqf_(fmaxf(h2C, 1e-38f));
        const float c2C = fmaf(0.5f * fabsf(ddC), rhC, 0.5f);
        const float rcC = rsqf_(c2C);
        const float ccC = (h2C > 1e-38f) ? c2C * rcC : 1.0f;
        const float tC  = aC * (rhC * rcC);
        const float sC  = (ddC < 0.0f) ? -tC : tC;
        // Z' = J^T (Z J): 6 fma from the 4 pre-fetched elements
        const float t0 = fmaf(sC, zc,  ccC * z);
        const float t1 = fmaf(sC, zrc, ccC * zr);
        z = fmaf(sR, t1, ccR * t0);
        // W row op
        W = fmaf(sR, Wr, ccR * W);
      });
    };
    jacobi_sweep();
    jacobi_sweep();
#pragma unroll 1
    for (int s = 2; s < 6; ++s) {
      const bool off = (i < j) && (z * z > s2);
      if (__ballot(off) == 0ull) break;
      jacobi_sweep();
    }

    // ---- eigen weights on diag lanes: ev^tk = 2^(tk*log2(ev)) ----
    const float evd = (i == j) ? fmaxf(z, 1e-10f) : 1.0f;
    const float wd  = __builtin_amdgcn_exp2f(tk * __builtin_amdgcn_logf(evd));

    // ---- U = W^T ; Mn = U diag(wd) U^T (all fetches independent) ----
    const float U = bper(tp, W);
    float mn = 0.0f;
    sfor<8>([&](auto KK) {
      constexpr int kk = KK.value;
      const float wk  = rl(wd, 9 * kk);
      const float uik = bper(ii5 | (kk << 2), U);
      const float ujk = bper(jj5 | (kk << 2), U);
      mn = fmaf(wk * uik, ujk, mn);
    });
    M = 0.5f * (mn + bper(tp, mn));
    Xc = Xn;
  }

  out[(size_t)((b * 16 + o) * 81 + r81) * 64 + lane] = M;
}

extern "C" void kernel_launch(void* const* d_in, const int* in_sizes, int n_in,
                              void* d_out, int out_size, void* d_ws, size_t ws_size,
                              hipStream_t stream) {
  const float* x  = (const float*)d_in[0];
  const float* wm = (const float*)d_in[1];
  float* out = (float*)d_out;
  // 5184 chains, 1 wave each, 2 waves per 128-thread block -> 2592 blocks
  spd_fm_kernel<<<2592, 128, 0, stream>>>(x, wm, out);
}

// Round 10
// 941.878 us; speedup vs baseline: 1.4379x; 1.4379x over previous
//
#include <hip/hip_runtime.h>
#include <utility>

// SPDConv2D: recursive weighted geometric mean of 8x8 SPD matrices.
// One wave per (o,site) chain; lane l holds element (i,j)=(l>>3,l&7).
// R9: R8 + FIX: rotation sign tie-break by pair order when dd==0 exactly
//     (previously both partners chose +tt -> singular rank-1 transform ->
//     NaN cascade). Tolerance reverted to R6-proven 1.6e-8.
//     Jacobi round = 6 DS (4 parallel + 2 parallel-after-G), ~20 VALU.

static __device__ __forceinline__ float bper(int byteidx, float v) {
  return __int_as_float(__builtin_amdgcn_ds_bpermute(byteidx, __float_as_int(v)));
}
static __device__ __forceinline__ float rl(float v, int lane_u) {
  return __int_as_float(__builtin_amdgcn_readlane(__float_as_int(v), lane_u));
}
static __device__ __forceinline__ float rcpf_(float x) { return __builtin_amdgcn_rcpf(x); }
static __device__ __forceinline__ float rsqf_(float x) { return __builtin_amdgcn_rsqf(x); }

// Broadcast octet position R (0..7) to all 8 lanes of each octet (DPP only).
template <int R>
static __device__ __forceinline__ float obcast(float v, bool hi) {
  const int x = __float_as_int(v);
  const int a = __builtin_amdgcn_update_dpp(0, x, (R & 3) * 0x55, 0xF, 0xF, false);
  const int m = __builtin_amdgcn_update_dpp(0, a, 0x141, 0xF, 0xF, false);
  const int r = (R < 4) ? (hi ? m : a) : (hi ? a : m);
  return __int_as_float(r);
}

template <class F, int... Is>
static __device__ __forceinline__ void sfor_impl(F&& f, std::integer_sequence<int, Is...>) {
  (f(std::integral_constant<int, Is>{}), ...);
}
template <int N, class F>
static __device__ __forceinline__ void sfor(F&& f) {
  sfor_impl(static_cast<F&&>(f), std::make_integer_sequence<int, N>{});
}

__global__ __launch_bounds__(128) void spd_fm_kernel(
    const float* __restrict__ x,      // (4,8,20,20,8,8) f32
    const float* __restrict__ wm,     // (16,72) f32
    float* __restrict__ out)          // (4,16,9,9,8,8) f32
{
  const int wid = blockIdx.x * 2 + (threadIdx.x >> 6);
  if (wid >= 16 * 324) return;
  const int lane = threadIdx.x & 63;
  const int i = lane >> 3, j = lane & 7;
  const bool hi = (lane & 4) != 0;

  const int o    = wid / 324;
  const int site = wid - o * 324;
  const int b   = site / 81;
  const int r81 = site - b * 81;
  const int ho  = r81 / 9;
  const int wo  = r81 - ho * 9;

  const float* xb   = x + b * 204800 + (ho * 2) * 1280 + (wo * 2) * 64 + lane;
  const float* wrow = wm + o * 72;

  const int tp      = (((j << 3) | i)) << 2;  // transpose byte-index
  const int jj5     = j << 5;                 // byte base for src=(j<<3)|kk
  const int ii5     = i << 5;                 // byte base for src=(i<<3)|kk
  const int j2      = j << 2;                 // byte base for src=(r<<3)|j
  const int bx_ii   = (i * 9) << 2;           // lane (i,i)
  const int bx_self = lane << 2;              // own lane

  // t[o,k] = w^2/cumsum(w^2) (eps cancels); t0 == 1 => M = sym(X_0)
  float w0 = wrow[0];
  float csum = w0 * w0;
  float M = xb[0];
  M = 0.5f * (M + bper(tp, M));

  float Xc = xb[25600];  // k=1: kh=0,kw=0,c=1
  for (int k = 1; k < 72; ++k) {
    // prefetch X for k+1
    float Xn = 0.0f;
    if (k + 1 < 72) {
      const int k1 = k + 1;
      const int kh = k1 / 24;
      const int rr = k1 - kh * 24;
      Xn = xb[(rr & 7) * 25600 + kh * 1280 + (rr >> 3) * 64];
    }

    float wv = wrow[k];
    wv *= wv;
    csum += wv;
    const float tk = wv * rcpf_(csum);

    // ---- Cholesky M = L L^T ----
    float a = M;
    float dinv = 0.0f;  // diag lanes hold 1/L_kk
    sfor<8>([&](auto KK) {
      constexpr int kk = KK.value;
      const float akk  = fmaxf(rl(a, 9 * kk), 1e-20f);
      const float rinv = rsqf_(akk);
      if (j == kk) a = (i == kk) ? akk * rinv : a * rinv;
      if (i == kk && j == kk) dinv = rinv;
      const float lik = obcast<kk>(a, hi);          // L[i][kk] via DPP
      const float ljk = bper(jj5 | (kk << 2), a);   // L[j][kk]
      if (i > kk && j > kk) a = fmaf(-lik, ljk, a);
    });
    const float Lm = (j <= i) ? a : 0.0f;

    // prefetch L[i][r] for both solves: 8 independent bpermutes
    float lir[8];
    sfor<8>([&](auto RR) {
      constexpr int r = RR.value;
      lir[r] = bper(ii5 | (r << 2), Lm);
    });

    // ---- Y = L^{-1} X ----
    float y = Xc;
    sfor<8>([&](auto RR) {
      constexpr int r = RR.value;
      const float dr = rl(dinv, 9 * r);
      if (i == r) y *= dr;
      const float yr = bper((r << 5) | j2, y);      // Y[r][j] (serial)
      if (i > r) y = fmaf(-lir[r], yr, y);
    });

    // ---- Z = L^{-1} Y^T ----
    float z = bper(tp, y);
    sfor<8>([&](auto RR) {
      constexpr int r = RR.value;
      const float dr = rl(dinv, 9 * r);
      if (i == r) z *= dr;
      const float zr = bper((r << 5) | j2, z);
      if (i > r) z = fmaf(-lir[r], zr, z);
    });
    z = 0.5f * (z + bper(tp, z));

    // trace is rotation-invariant -> fixed absolute scale for convergence
    float trz = 0.0f;
#pragma unroll
    for (int d = 0; d < 8; ++d) trz += rl(z, 9 * d);
    const float s2 = 1.6e-8f * trz * trz;  // (~1e-3 * tr/8)^2

    // ---- XOR-paired Jacobi (transpose trick), replicated diag D,
    //      W = (L * prod J)^T maintained by row-ops ----
    float W = bper(tp, Lm);
    float D = bper(bx_ii, z);               // Z[i][i], replicated along row
    auto jacobi_sweep = [&]() {
      sfor<7>([&](auto RR) {
        constexpr int r   = RR.value + 1;
        constexpr int xc  = r << 2;         // col-field xor on byte addr
        constexpr int xr  = r << 5;         // row-field xor on byte addr
        constexpr int msb = (r >= 4) ? 4 : ((r >= 2) ? 2 : 1);  // pair order bit
        // ONE parallel DS level (4 fetches):
        const float zr = bper(bx_self ^ xr, z);   // Z[i^r][j]
        const float aR = bper(bx_ii ^ xc, z);     // Z[i][i^r]
        const float Dq = bper(bx_self ^ xr, D);   // Z[i^r][i^r]
        const float Wr = bper(bx_self ^ xr, W);   // W[i^r][j]
        // rotation for pair {i, i^r}; sign antisymmetric across partners,
        // tie at dd==0 broken by pair order (i smaller -> +tt).
        const float dd = D - Dq;
        const float q2 = aR + aR;
        const float h2 = fmaf(dd, dd, q2 * q2);
        const float rh = rsqf_(fmaxf(h2, 1e-38f));
        const float c2 = fmaf(0.5f * fabsf(dd), rh, 0.5f);
        const float rc = rsqf_(c2);
        const bool ok  = h2 > 1e-38f;
        const float cc = ok ? c2 * rc : 1.0f;
        const float tt = aR * (rh * rc);
        const bool neg = (dd < 0.0f) || ((dd == 0.0f) && ((i & msb) != 0));
        float sR = neg ? -tt : tt;
        sR = ok ? sR : 0.0f;
        // row op: G = J^T Z ; W' = J^T W ; local diag update (exact)
        const float G = fmaf(sR, zr, cc * z);
        W = fmaf(sR, Wr, cc * W);
        D = fmaf(cc, fmaf(cc, D, sR * aR), sR * fmaf(cc, aR, sR * Dq));
        // second level: z' = J^T G^T (two independent fetches from G)
        const float T  = bper(tp, G);        // G[j][i]
        const float T2 = bper(tp ^ xc, G);   // G[j][i^r]
        z = fmaf(sR, T2, cc * T);
      });
    };
    jacobi_sweep();
    jacobi_sweep();
#pragma unroll 1
    for (int s = 2; s < 6; ++s) {
      const bool off = (i < j) && (z * z > s2);
      if (__ballot(off) == 0ull) break;
      jacobi_sweep();
    }

    // ---- eigen weights on diag lanes: ev^tk = 2^(tk*log2(ev)) ----
    const float evd = (i == j) ? fmaxf(z, 1e-10f) : 1.0f;
    const float wd  = __builtin_amdgcn_exp2f(tk * __builtin_amdgcn_logf(evd));

    // ---- U = W^T ; Mn = U diag(wd) U^T (all fetches independent) ----
    const float U = bper(tp, W);
    float mn = 0.0f;
    sfor<8>([&](auto KK) {
      constexpr int kk = KK.value;
      const float wk  = rl(wd, 9 * kk);
      const float uik = bper(ii5 | (kk << 2), U);
      const float ujk = bper(jj5 | (kk << 2), U);
      mn = fmaf(wk * uik, ujk, mn);
    });
    M = 0.5f * (mn + bper(tp, mn));
    Xc = Xn;
  }

  out[(size_t)((b * 16 + o) * 81 + r81) * 64 + lane] = M;
}

extern "C" void kernel_launch(void* const* d_in, const int* in_sizes, int n_in,
                              void* d_out, int out_size, void* d_ws, size_t ws_size,
                              hipStream_t stream) {
  const float* x  = (const float*)d_in[0];
  const float* wm = (const float*)d_in[1];
  float* out = (float*)d_out;
  // 5184 chains, 1 wave each, 2 waves per 128-thread block -> 2592 blocks
  spd_fm_kernel<<<2592, 128, 0, stream>>>(x, wm, out);
}

// Round 11
// 770.133 us; speedup vs baseline: 1.7586x; 1.2230x over previous
//
#include <hip/hip_runtime.h>
#include <utility>

// SPDConv2D: recursive weighted geometric mean of 8x8 SPD matrices.
// One wave per (o,site) chain; lane l holds element (i,j)=(l>>3,l&7).
// R10: ds_swizzle immediates (lir, uik, Jacobi r<4, trz-xor16),
//      trz via xor-tree on replicated diag D, looser sweep tolerance
//      (rel ~5e-3) + cap 5 sweeps, 64-thread blocks for tail balance.

static __device__ __forceinline__ float bper(int byteidx, float v) {
  return __int_as_float(__builtin_amdgcn_ds_bpermute(byteidx, __float_as_int(v)));
}
static __device__ __forceinline__ float rl(float v, int lane_u) {
  return __int_as_float(__builtin_amdgcn_readlane(__float_as_int(v), lane_u));
}
template <int P>
static __device__ __forceinline__ float swz(float v) {
  return __int_as_float(__builtin_amdgcn_ds_swizzle(__float_as_int(v), P));
}
static __device__ __forceinline__ float dpp_ror8(float v) {
  // within each 16-lane row, rotate by 8 == lane^8 (row-field bit0 of i)
  return __int_as_float(__builtin_amdgcn_update_dpp(0, __float_as_int(v), 0x128, 0xF, 0xF, true));
}
static __device__ __forceinline__ float rcpf_(float x) { return __builtin_amdgcn_rcpf(x); }
static __device__ __forceinline__ float rsqf_(float x) { return __builtin_amdgcn_rsqf(x); }

// Broadcast octet position R (0..7) to all 8 lanes of each octet (DPP only).
template <int R>
static __device__ __forceinline__ float obcast(float v, bool hi) {
  const int x = __float_as_int(v);
  const int a = __builtin_amdgcn_update_dpp(0, x, (R & 3) * 0x55, 0xF, 0xF, false);
  const int m = __builtin_amdgcn_update_dpp(0, a, 0x141, 0xF, 0xF, false);
  const int r = (R < 4) ? (hi ? m : a) : (hi ? a : m);
  return __int_as_float(r);
}

template <class F, int... Is>
static __device__ __forceinline__ void sfor_impl(F&& f, std::integer_sequence<int, Is...>) {
  (f(std::integral_constant<int, Is>{}), ...);
}
template <int N, class F>
static __device__ __forceinline__ void sfor(F&& f) {
  sfor_impl(static_cast<F&&>(f), std::make_integer_sequence<int, N>{});
}

__global__ __launch_bounds__(64) void spd_fm_kernel(
    const float* __restrict__ x,      // (4,8,20,20,8,8) f32
    const float* __restrict__ wm,     // (16,72) f32
    float* __restrict__ out)          // (4,16,9,9,8,8) f32
{
  const int wid = blockIdx.x;
  const int lane = threadIdx.x;
  const int i = lane >> 3, j = lane & 7;
  const bool hi = (lane & 4) != 0;

  const int o    = wid / 324;
  const int site = wid - o * 324;
  const int b   = site / 81;
  const int r81 = site - b * 81;
  const int ho  = r81 / 9;
  const int wo  = r81 - ho * 9;

  const float* xb   = x + b * 204800 + (ho * 2) * 1280 + (wo * 2) * 64 + lane;
  const float* wrow = wm + o * 72;

  const int tp      = (((j << 3) | i)) << 2;  // transpose byte-index
  const int jj5     = j << 5;                 // byte base for src=(j<<3)|kk
  const int j2      = j << 2;                 // byte base for src=(r<<3)|j
  const int bx_ii   = (i * 9) << 2;           // lane (i,i)
  const int bx_self = lane << 2;              // own lane

  // t[o,k] = w^2/cumsum(w^2) (eps cancels); t0 == 1 => M = sym(X_0)
  float w0 = wrow[0];
  float csum = w0 * w0;
  float M = xb[0];
  M = 0.5f * (M + bper(tp, M));

  float Xc = xb[25600];  // k=1: kh=0,kw=0,c=1
  for (int k = 1; k < 72; ++k) {
    // prefetch X for k+1
    float Xn = 0.0f;
    if (k + 1 < 72) {
      const int k1 = k + 1;
      const int kh = k1 / 24;
      const int rr = k1 - kh * 24;
      Xn = xb[(rr & 7) * 25600 + kh * 1280 + (rr >> 3) * 64];
    }

    float wv = wrow[k];
    wv *= wv;
    csum += wv;
    const float tk = wv * rcpf_(csum);

    // ---- Cholesky M = L L^T ----
    float a = M;
    float dinv = 0.0f;  // diag lanes hold 1/L_kk
    sfor<8>([&](auto KK) {
      constexpr int kk = KK.value;
      const float akk  = fmaxf(rl(a, 9 * kk), 1e-20f);
      const float rinv = rsqf_(akk);
      if (j == kk) a = (i == kk) ? akk * rinv : a * rinv;
      if (i == kk && j == kk) dinv = rinv;
      const float lik = obcast<kk>(a, hi);          // L[i][kk] via DPP
      const float ljk = bper(jj5 | (kk << 2), a);   // L[j][kk]
      if (i > kk && j > kk) a = fmaf(-lik, ljk, a);
    });
    const float Lm = (j <= i) ? a : 0.0f;

    // prefetch L[i][r]: immediate swizzles (and=0x18 keeps i-bits, or=r)
    float lir[8];
    sfor<8>([&](auto RR) {
      constexpr int r = RR.value;
      lir[r] = swz<(r << 5) | 0x18>(Lm);
    });

    // ---- Y = L^{-1} X ----
    float y = Xc;
    sfor<8>([&](auto RR) {
      constexpr int r = RR.value;
      const float dr = rl(dinv, 9 * r);
      if (i == r) y *= dr;
      const float yr = bper((r << 5) | j2, y);      // Y[r][j] (serial)
      if (i > r) y = fmaf(-lir[r], yr, y);
    });

    // ---- Z = L^{-1} Y^T ----
    float z = bper(tp, y);
    sfor<8>([&](auto RR) {
      constexpr int r = RR.value;
      const float dr = rl(dinv, 9 * r);
      if (i == r) z *= dr;
      const float zr = bper((r << 5) | j2, z);
      if (i > r) z = fmaf(-lir[r], zr, z);
    });
    z = 0.5f * (z + bper(tp, z));

    // ---- replicated diag D; trace via xor-tree on D (invariant) ----
    float D = bper(bx_ii, z);               // Z[i][i], replicated along row
    float t8 = D + dpp_ror8(D);             // + i^1
    t8 += swz<0x401F>(t8);                  // + i^2
    const float trz = t8 + bper(bx_self ^ 128, t8);  // + i^4
    const float s2 = 3.9e-7f * trz * trz;   // (~5e-3 * tr/8)^2

    // ---- XOR-paired Jacobi (transpose trick), W = (L*prodJ)^T ----
    float W = bper(tp, Lm);
    auto jacobi_sweep = [&]() {
      sfor<7>([&](auto RR) {
        constexpr int r   = RR.value + 1;
        constexpr int xc  = r << 2;         // col-field xor on byte addr
        constexpr int xr  = r << 5;         // row-field xor on byte addr
        constexpr int msb = (r >= 4) ? 4 : ((r >= 2) ? 2 : 1);  // pair order bit
        float zr, Dq, Wr;
        if constexpr (r < 4) {
          constexpr int P = ((r << 3) << 10) | 0x1F;  // lane ^ (r<<3), in-half
          zr = swz<P>(z);
          Dq = swz<P>(D);
          Wr = swz<P>(W);
        } else {
          zr = bper(bx_self ^ xr, z);
          Dq = bper(bx_self ^ xr, D);
          Wr = bper(bx_self ^ xr, W);
        }
        const float aR = bper(bx_ii ^ xc, z);     // Z[i][i^r]
        // rotation for pair {i, i^r}; antisymmetric sign, tie-break by order
        const float dd = D - Dq;
        const float q2 = aR + aR;
        const float h2 = fmaf(dd, dd, q2 * q2);
        const float rh = rsqf_(fmaxf(h2, 1e-38f));
        const float c2 = fmaf(0.5f * fabsf(dd), rh, 0.5f);
        const float rc = rsqf_(c2);
        const bool ok  = h2 > 1e-38f;
        const float cc = ok ? c2 * rc : 1.0f;
        const float tt = aR * (rh * rc);
        const bool neg = (dd < 0.0f) || ((dd == 0.0f) && ((i & msb) != 0));
        float sR = neg ? -tt : tt;
        sR = ok ? sR : 0.0f;
        // row op: G = J^T Z ; W' = J^T W ; local diag update (exact)
        const float G = fmaf(sR, zr, cc * z);
        W = fmaf(sR, Wr, cc * W);
        D = fmaf(cc, fmaf(cc, D, sR * aR), sR * fmaf(cc, aR, sR * Dq));
        // second level: z' = J^T G^T (two independent fetches from G)
        const float T  = bper(tp, G);        // G[j][i]
        const float T2 = bper(tp ^ xc, G);   // G[j][i^r]
        z = fmaf(sR, T2, cc * T);
      });
    };
    jacobi_sweep();
    jacobi_sweep();
#pragma unroll 1
    for (int s = 2; s < 5; ++s) {
      const bool off = (i < j) && (z * z > s2);
      if (__ballot(off) == 0ull) break;
      jacobi_sweep();
    }

    // ---- eigen weights on diag lanes: ev^tk = 2^(tk*log2(ev)) ----
    const float evd = (i == j) ? fmaxf(z, 1e-10f) : 1.0f;
    const float wd  = __builtin_amdgcn_exp2f(tk * __builtin_amdgcn_logf(evd));

    // ---- U = W^T ; Mn = U diag(wd) U^T ----
    const float U = bper(tp, W);
    float mn = 0.0f;
    sfor<8>([&](auto KK) {
      constexpr int kk = KK.value;
      const float wk  = rl(wd, 9 * kk);
      const float uik = swz<(kk << 5) | 0x18>(U);   // U[i][kk], imm swizzle
      const float ujk = bper(jj5 | (kk << 2), U);   // U[j][kk]
      mn = fmaf(wk * uik, ujk, mn);
    });
    M = 0.5f * (mn + bper(tp, mn));
    Xc = Xn;
  }

  out[(size_t)((b * 16 + o) * 81 + r81) * 64 + lane] = M;
}

extern "C" void kernel_launch(void* const* d_in, const int* in_sizes, int n_in,
                              void* d_out, int out_size, void* d_ws, size_t ws_size,
                              hipStream_t stream) {
  const float* x  = (const float*)d_in[0];
  const float* wm = (const float*)d_in[1];
  float* out = (float*)d_out;
  // 5184 chains, 1 wave each, 1 wave per block -> finest tail granularity
  spd_fm_kernel<<<5184, 64, 0, stream>>>(x, wm, out);
}